// Round 6
// baseline (358.965 us; speedup 1.0000x reference)
//
#include <hip/hip_runtime.h>
#include <hip/hip_bf16.h>
#include <math.h>

#define VV 50257   // vocab
#define VP 50304   // vocab padded to multiple of 128 (and 16)
#define HH 512     // d_model
#define SS 512     // source length
#define BB 8       // batch
#define TT 64      // decode steps
#define MM (TT*BB) // 512 GEMM rows

typedef __bf16 bf16x2 __attribute__((ext_vector_type(2)));
typedef __bf16 bf16x4 __attribute__((ext_vector_type(4)));
typedef __bf16 bf16x8 __attribute__((ext_vector_type(8)));
typedef float  f32x4  __attribute__((ext_vector_type(4)));

// fp32 -> bf16 RNE
__device__ __forceinline__ __bf16 f2b(float f) {
    unsigned u = __builtin_bit_cast(unsigned, f);
    unsigned r = (u + 0x7fffu + ((u >> 16) & 1u)) >> 16;
    unsigned short s = (unsigned short)r;
    return __builtin_bit_cast(__bf16, s);
}

// async global->LDS, 16B per lane; lds base must be wave-uniform
__device__ __forceinline__ void gl2lds16(const void* g, void* l) {
    __builtin_amdgcn_global_load_lds(
        (const __attribute__((address_space(1))) unsigned*)g,
        (__attribute__((address_space(3))) unsigned*)l, 16, 0, 0);
}

#define WAITV(n) asm volatile("s_waitcnt vmcnt(" #n ")" ::: "memory")

// ---------------------------------------------------------------------------
// L1: blocks [0,256):      cast decode_output fp32 -> bf16
//     blocks [256,1280):   mw[s,b] = dot(memory[s,b,:], W_prob), 4 rows/blk
// (mw is a PRODUCER for L2's prob branch — must be a separate launch; an
//  intra-launch producer/consumer split would race: no inter-block ordering.)
// ---------------------------------------------------------------------------
__global__ __launch_bounds__(256) void k_pre0(const float* __restrict__ A,
                                              __bf16* __restrict__ Ab,
                                              const float* __restrict__ mem,
                                              const float* __restrict__ Wp,
                                              float* __restrict__ mw) {
    int tid = threadIdx.x;
    if (blockIdx.x < 256) {
        int i = (blockIdx.x * 256 + tid) * 4;
        float4 v = *(const float4*)&A[i];
        bf16x4 o = {f2b(v.x), f2b(v.y), f2b(v.z), f2b(v.w)};
        *(bf16x4*)&Ab[i] = o;
    } else {
        int bx = blockIdx.x - 256;
        int row = bx * 4 + (tid >> 6);        // 0..4095
        int lane = tid & 63;
        const float* mp = mem + (size_t)row * HH;
        float acc = 0.f;
#pragma unroll
        for (int i = 0; i < HH / 64; i++)
            acc += mp[lane + 64 * i] * Wp[lane + 64 * i];
#pragma unroll
        for (int off = 32; off > 0; off >>= 1) acc += __shfl_down(acc, off);
        if (lane == 0) mw[row] = acc;
    }
}

// ---------------------------------------------------------------------------
// L2: blocks [0,1572):     W fp32 [HH][VV] -> Wt bf16 [VP][HH], 32-vocab
//                          strips over full K; double-buffered tile, ONE
//                          barrier per 32-k chunk; 1KB-contiguous output.
//     blocks [1572,2084):  prob[r] = sigmoid(attn . mw + b); Z[r] = 0
// ---------------------------------------------------------------------------
#define NWT (VP / 32)   // 1572
__global__ __launch_bounds__(256) void k_wt2(const float* __restrict__ W,
                                             __bf16* __restrict__ Wt,
                                             const float* __restrict__ attn,
                                             const float* __restrict__ mw,
                                             const float* __restrict__ bp,
                                             float* __restrict__ prob,
                                             float* __restrict__ Z) {
    __shared__ float tile[2][32][33];    // 8.4 KB double-buffered
    __shared__ __bf16 Wo[32][520];       // 33.3 KB (+8 bf16 row pad)
    int tid = threadIdx.x;

    if (blockIdx.x < NWT) {
        int n0 = blockIdx.x * 32;
        int nn = tid >> 3, ks = (tid & 7) * 4;
#pragma unroll
        for (int kc = 0; kc < 16; kc++) {
            int k0 = kc * 32;
            int p = kc & 1;
            // load 32k x 32n fp32, coalesced 128B per k-row
#pragma unroll
            for (int rd = 0; rd < 4; rd++) {
                int idx = rd * 256 + tid;
                int kk = idx >> 5, nc = idx & 31;
                int n = n0 + nc;
                tile[p][kk][nc] = (n < VV) ? W[(size_t)(k0 + kk) * VV + n] : 0.f;
            }
            __syncthreads();   // loads(kc) done AND transposes(kc-1) done
            bf16x4 o = {f2b(tile[p][ks][nn]), f2b(tile[p][ks + 1][nn]),
                        f2b(tile[p][ks + 2][nn]), f2b(tile[p][ks + 3][nn])};
            *(bf16x4*)&Wo[nn][k0 + ks] = o;
        }
        __syncthreads();
        // burst out: 32 rows x 1KB fully contiguous
#pragma unroll
        for (int i = 0; i < 8; i++) {
            int r = i * 4 + (tid >> 6);
            int c = (tid & 63) * 8;
            *(bf16x8*)&Wt[(size_t)(n0 + r) * HH + c] = *(const bf16x8*)&Wo[r][c];
        }
    } else {
        int r = blockIdx.x - NWT;
        int t = r / BB, b = r % BB;
        const float* ap = attn + ((size_t)b * TT + t) * SS;
        float acc = ap[tid] * mw[tid * BB + b] +
                    ap[tid + 256] * mw[(tid + 256) * BB + b];
        float* red = &tile[0][0][0];
        red[tid] = acc; __syncthreads();
        for (int st = 128; st > 0; st >>= 1) {
            if (tid < st) red[tid] += red[tid + st];
            __syncthreads();
        }
        if (tid == 0) {
            prob[r] = 1.f / (1.f + expf(-(red[0] + bp[0])));
            Z[r] = 0.f;
        }
    }
}

// ---------------------------------------------------------------------------
// K3: MFMA GEMM, tile BM=256 x BN=128, BK=32, 16 k-iters. Halves block count
// (786) and A-staging traffic vs 128x128; 16 MFMA + 8 ds_read_b128 per wave
// per slot (2x compute per staged byte). 3 LDS buffers (72.75 KB -> 2
// blocks/CU, 16 waves), prefetch depth 2, raw s_barrier + counted WAITV(3)
// (3 loads/wave/iter: 2 A-segs + 1 B-seg). s_setprio around MFMA cluster.
// Wave w owns 64x64: wr=(w>>1)*64, wc=(w&1)*64. k-accumulation order per
// 16x16 fragment unchanged (bit-identical C vs previous rounds).
// ---------------------------------------------------------------------------
template<bool BF16OUT>
__global__ __launch_bounds__(512, 4) void k_gemm6(const __bf16* __restrict__ Ab,
                                                  const __bf16* __restrict__ Wt,
                                                  const float* __restrict__ bias,
                                                  float* __restrict__ Cf,
                                                  __bf16* __restrict__ Cb,
                                                  float* __restrict__ Zrow) {
    __shared__ __bf16 As[3][8192];   // 3 bufs x 16KB: 16 segs x 16 rows x 32k
    __shared__ __bf16 Bs[3][4096];   // 3 bufs x 8KB:   8 segs
    __shared__ float zred[256];

    const int tid  = threadIdx.x;
    const int lane = tid & 63;
    const int wave = tid >> 6;          // 0..7
    const int l15  = lane & 15;
    const int quad = lane >> 4;
    const int wr = (wave >> 1) * 64;    // 0,64,128,192
    const int wc = (wave & 1) * 64;     // 0,64

    // bijective XCD swizzle over the 786-block grid (q=98, r=2)
    int L = blockIdx.x + gridDim.x * blockIdx.y;
    int xcd = L & 7, i8 = L >> 3;
    int nid = (xcd < 2 ? xcd * 99 : 2 * 99 + (xcd - 2) * 98) + i8;
    const int row0 = (nid & 1) * 256;   // row fastest: B-panel L2 reuse
    const int col0 = (nid >> 1) * 128;

    // wave w stages A segs {2w, 2w+1} and B seg w.
    // global (row = seg*16 + l15, k = quad*8..+8) -> LDS seg*1024B + 16B*lane
    size_t offA[2];
#pragma unroll
    for (int q = 0; q < 2; q++)
        offA[q] = (size_t)(row0 + (2 * wave + q) * 16 + l15) * HH + quad * 8;
    const size_t offB = (size_t)(col0 + wave * 16 + l15) * HH + quad * 8;

#define STAGE(buf, k0)                                                       \
    do {                                                                     \
        gl2lds16(Ab + offA[0] + (k0), &As[buf][(2 * wave) * 512]);           \
        gl2lds16(Ab + offA[1] + (k0), &As[buf][(2 * wave + 1) * 512]);       \
        gl2lds16(Wt + offB + (k0),    &Bs[buf][wave * 512]);                 \
    } while (0)

    f32x4 acc[4][4] = {};

    STAGE(0, 0);
    STAGE(1, 32);
#pragma unroll
    for (int it = 0; it < 16; ++it) {
        if (it < 15) WAITV(3);   // tile it landed; tile it+1 stays in flight
        else         WAITV(0);
        __builtin_amdgcn_s_barrier();
        if (it < 14) STAGE((it + 2) % 3, (it + 2) * 32);
        const __bf16* Al = &As[it % 3][0];
        const __bf16* Bl = &Bs[it % 3][0];
        bf16x8 af[4], bfv[4];
#pragma unroll
        for (int mt = 0; mt < 4; mt++)
            af[mt] = *(const bf16x8*)&Al[((wr >> 4) + mt) * 512 + lane * 8];
#pragma unroll
        for (int nt = 0; nt < 4; nt++)
            bfv[nt] = *(const bf16x8*)&Bl[((wc >> 4) + nt) * 512 + lane * 8];
        __builtin_amdgcn_s_setprio(1);
#pragma unroll
        for (int mt = 0; mt < 4; mt++)
#pragma unroll
            for (int nt = 0; nt < 4; nt++)
                acc[mt][nt] = __builtin_amdgcn_mfma_f32_16x16x32_bf16(
                    af[mt], bfv[nt], acc[mt][nt], 0, 0, 0);
        __builtin_amdgcn_s_setprio(0);
    }
#undef STAGE

    __syncthreads();
    if (tid < 256) zred[tid] = 0.f;
    __syncthreads();

#pragma unroll
    for (int mt = 0; mt < 4; mt++) {
        float esum[4] = {0.f, 0.f, 0.f, 0.f};
#pragma unroll
        for (int nt = 0; nt < 4; nt++) {
            int c = col0 + wc + nt * 16 + l15;
            if (c < VV) {
                float bv = bias[c];
#pragma unroll
                for (int i = 0; i < 4; i++) {
                    int r = row0 + wr + mt * 16 + quad * 4 + i;
                    float l = acc[mt][nt][i] + bv;
                    if (BF16OUT) Cb[(size_t)r * VP + c] = f2b(l);
                    else         Cf[(size_t)r * VV + c] = l;
                    esum[i] += __expf(l);
                }
            }
        }
#pragma unroll
        for (int i = 0; i < 4; i++) {
            float e = esum[i];
            e += __shfl_xor(e, 1);
            e += __shfl_xor(e, 2);
            e += __shfl_xor(e, 4);
            e += __shfl_xor(e, 8);
            if (l15 == 0)
                atomicAdd(&zred[wr + mt * 16 + quad * 4 + i], e);
        }
    }
    __syncthreads();
    if (tid < 256) atomicAdd(&Zrow[row0 + tid], zred[tid]);
}

// ---------------------------------------------------------------------------
// K4 shared preamble (256-thread version, used by fallback k_final_s)
// ---------------------------------------------------------------------------
#define HT 1024
#define NBW 1572   // ceil(VV/32)

__device__ __forceinline__ void build_hash(const int* __restrict__ src,
                                           const float* __restrict__ ap,
                                           int b, int tid,
                                           int* keys, float* vals, unsigned* bmap,
                                           float* red, int* s_D, float* s_Zc) {
    for (int i = tid; i < HT; i += 256) { keys[i] = -1; vals[i] = 0.f; }
    for (int i = tid; i < NBW; i += 256) bmap[i] = 0u;
    if (tid == 0) *s_D = 0;
    __syncthreads();

    for (int s = tid; s < SS; s += 256) {
        int idx = src[s * BB + b];
        float v = ap[s];
        unsigned h = ((unsigned)idx * 2654435761u) >> 22;
        while (true) {
            int old = atomicCAS(&keys[h], -1, idx);
            if (old == -1 || old == idx) { atomicAdd(&vals[h], v); break; }
            h = (h + 1) & (HT - 1);
        }
    }
    __syncthreads();

    float lsum = 0.f; int dloc = 0;
    for (int i = tid; i < HT; i += 256) {
        int k = keys[i];
        if (k != -1) {
            lsum += __expf(vals[i]); dloc++;
            atomicOr(&bmap[(unsigned)k >> 5], 1u << (k & 31));
        }
    }
    atomicAdd(s_D, dloc);
    red[tid] = lsum; __syncthreads();
    for (int st = 128; st > 0; st >>= 1) {
        if (tid < st) red[tid] += red[tid + st];
        __syncthreads();
    }
    if (tid == 0) *s_Zc = (float)(VV - *s_D) + red[0];
    __syncthreads();
}

// ---------------------------------------------------------------------------
// K4a: finalize from bf16 padded logits. Grid (2, MM): each block handles
// half the vocab of one row. Clean 8-packs (bitmap byte == 0, ~92%) take a
// guard-free path: no hash probe, no bounds check, straight exp/log +
// unconditional coalesced stores.
// ---------------------------------------------------------------------------
#define HV (VP / 2)   // 25152, multiple of 8
__global__ __launch_bounds__(1024) void k_final2(const int* __restrict__ src,
                                                 const float* __restrict__ attn,
                                                 const float* __restrict__ prob,
                                                 const float* __restrict__ Zrow,
                                                 const __bf16* __restrict__ LG,
                                                 float* __restrict__ out) {
    __shared__ int      keys[HT];
    __shared__ float    vals[HT];
    __shared__ unsigned bmap[NBW];
    __shared__ float    red[1024];
    __shared__ int      s_D;
    __shared__ float    s_Zc;

    int r = blockIdx.y;
    int half = blockIdx.x;
    int t = r / BB, b = r % BB;
    int tid = threadIdx.x;
    const float* ap = attn + ((size_t)b * TT + t) * SS;

    // ---- build hash (1024 threads; HT == 1024) ----
    { keys[tid] = -1; vals[tid] = 0.f; }
    for (int i = tid; i < NBW; i += 1024) bmap[i] = 0u;
    if (tid == 0) s_D = 0;
    __syncthreads();

    if (tid < SS) {
        int idx = src[tid * BB + b];
        float v = ap[tid];
        unsigned h = ((unsigned)idx * 2654435761u) >> 22;
        while (true) {
            int old = atomicCAS(&keys[h], -1, idx);
            if (old == -1 || old == idx) { atomicAdd(&vals[h], v); break; }
            h = (h + 1) & (HT - 1);
        }
    }
    __syncthreads();

    float lsum = 0.f;
    {
        int k = keys[tid];
        bool occ = (k != -1);
        if (occ) {
            lsum = __expf(vals[tid]);
            atomicOr(&bmap[(unsigned)k >> 5], 1u << (k & 31));
        }
        unsigned long long m = __ballot(occ);
        if ((tid & 63) == 0) atomicAdd(&s_D, __popcll(m));
    }
    red[tid] = lsum; __syncthreads();
    for (int st = 512; st > 0; st >>= 1) {
        if (tid < st) red[tid] += red[tid + st];
        __syncthreads();
    }
    if (tid == 0) s_Zc = (float)(VV - s_D) + red[0];
    __syncthreads();

    float p = prob[r];
    float pinvZ = p / Zrow[r];
    float qinvZc = (1.f - p) / s_Zc;

    const __bf16* lrow = LG + (size_t)r * VP;
    float* orow = out + (size_t)r * VV;

    int base = half * HV;
    for (int v0 = base + tid * 8; v0 < base + HV; v0 += 8192) {
        bf16x8 l8 = *(const bf16x8*)&lrow[v0];
        unsigned bits = (bmap[v0 >> 5] >> (v0 & 31)) & 0xFFu;  // v0%8==0
        if (bits == 0u && v0 + 8 <= VV) {
#pragma unroll
            for (int e = 0; e < 8; e++)
                orow[v0 + e] = __logf(pinvZ * __expf((float)l8[e]) + qinvZc);
        } else {
#pragma unroll
            for (int e = 0; e < 8; e++) {
                int v = v0 + e;
                if (v < VV) {
                    float l = (float)l8[e];
                    float c = 1.f;
                    if ((bits >> e) & 1u) {
                        unsigned h = ((unsigned)v * 2654435761u) >> 22;
                        while (true) {
                            int k = keys[h];
                            if (k == v) { c = __expf(vals[h]); break; }
                            if (k == -1) break;
                            h = (h + 1) & (HT - 1);
                        }
                    }
                    orow[v] = __logf(pinvZ * __expf(l) + qinvZc * c);
                }
            }
        }
    }
}

// ---------------------------------------------------------------------------
// K4b: fallback — finalize fp32 logits in-place in d_out
// ---------------------------------------------------------------------------
#define CHUNKS 6283
__global__ __launch_bounds__(256) void k_final_s(const int* __restrict__ src,
                                                 const float* __restrict__ attn,
                                                 const float* __restrict__ prob,
                                                 const float* __restrict__ Zrow,
                                                 float* __restrict__ out) {
    __shared__ int      keys[HT];
    __shared__ float    vals[HT];
    __shared__ unsigned bmap[NBW];
    __shared__ float    red[256];
    __shared__ int      s_D;
    __shared__ float    s_Zc;

    int r = blockIdx.y;
    int t = r / BB, b = r % BB;
    int tid = threadIdx.x;
    const float* ap = attn + ((size_t)b * TT + t) * SS;
    build_hash(src, ap, b, tid, keys, vals, bmap, red, &s_D, &s_Zc);

    float p = prob[r];
    float pinvZ = p / Zrow[r];
    float qinvZc = (1.f - p) / s_Zc;

    int c0 = blockIdx.x * CHUNKS;
    int c1 = c0 + CHUNKS; if (c1 > VV) c1 = VV;
    float* rowp = out + (size_t)r * VV;

    for (int v = c0 + tid; v < c1; v += 256) {
        float l = rowp[v];
        float c = 1.f;
        if ((bmap[v >> 5] >> (v & 31)) & 1u) {
            unsigned h = ((unsigned)v * 2654435761u) >> 22;
            while (true) {
                int k = keys[h];
                if (k == v) { c = __expf(vals[h]); break; }
                if (k == -1) break;
                h = (h + 1) & (HT - 1);
            }
        }
        rowp[v] = __logf(pinvZ * __expf(l) + qinvZc * c);
    }
}

// ---------------------------------------------------------------------------
extern "C" void kernel_launch(void* const* d_in, const int* in_sizes, int n_in,
                              void* d_out, int out_size, void* d_ws, size_t ws_size,
                              hipStream_t stream) {
    const int*   src_full      = (const int*)d_in[0];   // [S,B]
    const float* decode_output = (const float*)d_in[1]; // [T,B,H]
    const float* decode_attn   = (const float*)d_in[2]; // [B,T,S]
    const float* memory        = (const float*)d_in[3]; // [S,B,H]
    const float* W_gen         = (const float*)d_in[4]; // [H,V]
    const float* b_gen         = (const float*)d_in[5]; // [V]
    const float* W_prob        = (const float*)d_in[6]; // [H]
    const float* b_prob        = (const float*)d_in[7]; // [1]
    float* out = (float*)d_out;                         // [T,B,V]

    float* ws   = (float*)d_ws;
    float* mw   = ws;                        // 4096 floats
    float* prob = ws + 4096;                 // 512
    float* Z    = ws + 4608;                 // 512
    __bf16* Ab  = (__bf16*)(ws + 5120);      // 512*512 bf16
    __bf16* Wt  = (__bf16*)(ws + 5120 + 131072);   // VP*HH bf16 (51.5 MB)
    __bf16* LG  = Wt + (size_t)VP * HH;            // MM*VP bf16 (51.5 MB)

    size_t base_b = (size_t)(5120 + 131072) * sizeof(float);
    size_t wt_b   = (size_t)VP * HH * 2;
    size_t lg_b   = (size_t)MM * VP * 2;
    bool full = ws_size >= base_b + wt_b + lg_b;

    // L1: castA (256) + mw (1024) — mw producer must precede its consumers
    k_pre0<<<1280, 256, 0, stream>>>(decode_output, Ab, memory, W_prob, mw);
    // L2: Wt strips (1572) + prob/Z (512)
    k_wt2<<<NWT + 512, 256, 0, stream>>>(W_gen, Wt, decode_attn, mw, b_prob,
                                         prob, Z);

    dim3 ggrid(MM / 256, VP / 128);          // (2, 393)
    if (full) {
        k_gemm6<true><<<ggrid, 512, 0, stream>>>(Ab, Wt, b_gen, nullptr, LG, Z);
        dim3 fgrid(2, MM);                   // (2, 512)
        k_final2<<<fgrid, 1024, 0, stream>>>(src_full, decode_attn, prob, Z, LG, out);
    } else {
        k_gemm6<false><<<ggrid, 512, 0, stream>>>(Ab, Wt, b_gen, out, nullptr, Z);
        dim3 fgrid((VV + CHUNKS - 1) / CHUNKS, MM);  // (8, 512)
        k_final_s<<<fgrid, 256, 0, stream>>>(src_full, decode_attn, prob, Z, out);
    }
}

// Round 8
// 311.496 us; speedup vs baseline: 1.1524x; 1.1524x over previous
//
#include <hip/hip_runtime.h>
#include <hip/hip_bf16.h>
#include <math.h>

#define VV 50257   // vocab
#define VP 50304   // vocab padded to multiple of 128 (and 16)
#define HH 512     // d_model
#define SS 512     // source length
#define BB 8       // batch
#define TT 64      // decode steps
#define MM (TT*BB) // 512 GEMM rows

typedef __bf16 bf16x2 __attribute__((ext_vector_type(2)));
typedef __bf16 bf16x4 __attribute__((ext_vector_type(4)));
typedef __bf16 bf16x8 __attribute__((ext_vector_type(8)));
typedef float  f32x4  __attribute__((ext_vector_type(4)));
// under-aligned float4: W rows are only 4B-aligned (VV odd) — alignment-4
// vector type lets clang emit dword-aligned dwordx4 (HW-supported) safely.
typedef float f4u __attribute__((vector_size(16), aligned(4)));

// fp32 -> bf16 RNE
__device__ __forceinline__ __bf16 f2b(float f) {
    unsigned u = __builtin_bit_cast(unsigned, f);
    unsigned r = (u + 0x7fffu + ((u >> 16) & 1u)) >> 16;
    unsigned short s = (unsigned short)r;
    return __builtin_bit_cast(__bf16, s);
}

// async global->LDS, 16B per lane; lds base must be wave-uniform
__device__ __forceinline__ void gl2lds16(const void* g, void* l) {
    __builtin_amdgcn_global_load_lds(
        (const __attribute__((address_space(1))) unsigned*)g,
        (__attribute__((address_space(3))) unsigned*)l, 16, 0, 0);
}

#define WAITV(n) asm volatile("s_waitcnt vmcnt(" #n ")" ::: "memory")

// ---------------------------------------------------------------------------
// L1 (single pre-pass, no LDS, no barriers):
//  blocks [0,3200):        W fp32 [HH][VV] -> Wt8 bf16 [64][VP][8] k8-panels:
//                          Wt8[k>>3][n][k&7] = W[k][n]. Register transpose of
//                          an 8k x 4n block per thread: 8 coalesced row reads
//                          (4KB per row across the block), 4 contiguous 16B
//                          writes (block writes 16KB fully contiguous).
//  blocks [3200,3456):     cast decode_output fp32 -> bf16  (consumed by GEMM)
//  blocks [3456,4480):     mw[s,b] = dot(memory[s,b,:], W_prob)  (consumed by
//                          finalize, 2 launches later — no intra-launch race)
// ---------------------------------------------------------------------------
#define NW8 3200   // 50 n-chunks x 64 k8-panels
__global__ __launch_bounds__(256) void k_pre(const float* __restrict__ W,
                                             __bf16* __restrict__ Wt8,
                                             const float* __restrict__ A,
                                             __bf16* __restrict__ Ab,
                                             const float* __restrict__ mem,
                                             const float* __restrict__ Wp,
                                             float* __restrict__ mw) {
    int tid = threadIdx.x;
    int bx = blockIdx.x;
    if (bx < NW8) {
        int cx = bx % 50, kb = bx / 50;
        int nb = cx * 1024 + tid * 4;
        if (nb >= VP) return;               // last chunk overhang
        const float* Wr = W + (size_t)(kb * 8) * VV + nb;
        float v[8][4];
        if (nb + 4 <= VV) {
#pragma unroll
            for (int r = 0; r < 8; r++) {
                f4u x = *(const f4u*)(Wr + (size_t)r * VV);
#pragma unroll
                for (int j = 0; j < 4; j++) v[r][j] = x[j];
            }
        } else {
#pragma unroll
            for (int r = 0; r < 8; r++)
#pragma unroll
                for (int j = 0; j < 4; j++)
                    v[r][j] = (nb + j < VV) ? Wr[(size_t)r * VV + j] : 0.f;
        }
#pragma unroll
        for (int j = 0; j < 4; j++) {
            bf16x8 o = {f2b(v[0][j]), f2b(v[1][j]), f2b(v[2][j]), f2b(v[3][j]),
                        f2b(v[4][j]), f2b(v[5][j]), f2b(v[6][j]), f2b(v[7][j])};
            *(bf16x8*)&Wt8[((size_t)kb * VP + nb + j) * 8] = o;
        }
    } else if (bx < NW8 + 256) {
        int i = ((bx - NW8) * 256 + tid) * 4;
        float4 va = *(const float4*)&A[i];
        bf16x4 o = {f2b(va.x), f2b(va.y), f2b(va.z), f2b(va.w)};
        *(bf16x4*)&Ab[i] = o;
    } else {
        int bxm = bx - (NW8 + 256);
        int row = bxm * 4 + (tid >> 6);      // 0..4095
        int lane = tid & 63;
        const float* mp = mem + (size_t)row * HH;
        float acc = 0.f;
#pragma unroll
        for (int i = 0; i < HH / 64; i++)
            acc += mp[lane + 64 * i] * Wp[lane + 64 * i];
#pragma unroll
        for (int off = 32; off > 0; off >>= 1) acc += __shfl_down(acc, off);
        if (lane == 0) mw[row] = acc;
    }
}

// ---------------------------------------------------------------------------
// K3: MFMA GEMM, tile BM=256 x BN=128, BK=32, 16 k-iters, 3 LDS buffers,
// prefetch depth 2, raw s_barrier + counted WAITV(3), s_setprio around MFMA.
// B now staged from Wt8 k8-panels: identical LDS fragment layout and 16B/lane
// gl2lds — only the global address formula changed. Bit-identical numerics.
// ---------------------------------------------------------------------------
template<bool BF16OUT>
__global__ __launch_bounds__(512, 4) void k_gemm7(const __bf16* __restrict__ Ab,
                                                  const __bf16* __restrict__ Wt8,
                                                  const float* __restrict__ bias,
                                                  float* __restrict__ Cf,
                                                  __bf16* __restrict__ Cb,
                                                  float* __restrict__ Zrow) {
    __shared__ __bf16 As[3][8192];   // 3 bufs x 16KB: 16 segs x 16 rows x 32k
    __shared__ __bf16 Bs[3][4096];   // 3 bufs x 8KB:   8 segs
    __shared__ float zred[256];

    const int tid  = threadIdx.x;
    const int lane = tid & 63;
    const int wave = tid >> 6;          // 0..7
    const int l15  = lane & 15;
    const int quad = lane >> 4;
    const int wr = (wave >> 1) * 64;    // 0,64,128,192
    const int wc = (wave & 1) * 64;     // 0,64

    // bijective XCD swizzle over the 786-block grid (q=98, r=2)
    int L = blockIdx.x + gridDim.x * blockIdx.y;
    int xcd = L & 7, i8 = L >> 3;
    int nid = (xcd < 2 ? xcd * 99 : 2 * 99 + (xcd - 2) * 98) + i8;
    const int row0 = (nid & 1) * 256;   // row fastest: B-panel L2 reuse
    const int col0 = (nid >> 1) * 128;

    // A: wave w stages segs {2w,2w+1}: global (row=seg*16+l15, k=quad*8..+8)
    size_t offA[2];
#pragma unroll
    for (int q = 0; q < 2; q++)
        offA[q] = (size_t)(row0 + (2 * wave + q) * 16 + l15) * HH + quad * 8;
    // B: wave w stages seg w from Wt8[kb=(k0>>3)+quad][n=col0+w*16+l15][0..8]
    const size_t offB = (size_t)quad * VP * 8 +
                        (size_t)(col0 + wave * 16 + l15) * 8;

#define STAGE(buf, k0)                                                       \
    do {                                                                     \
        gl2lds16(Ab + offA[0] + (k0), &As[buf][(2 * wave) * 512]);           \
        gl2lds16(Ab + offA[1] + (k0), &As[buf][(2 * wave + 1) * 512]);       \
        gl2lds16(Wt8 + offB + (size_t)(k0) * VP, &Bs[buf][wave * 512]);      \
    } while (0)

    f32x4 acc[4][4] = {};

    STAGE(0, 0);
    STAGE(1, 32);
#pragma unroll
    for (int it = 0; it < 16; ++it) {
        if (it < 15) WAITV(3);   // tile it landed; tile it+1 stays in flight
        else         WAITV(0);
        __builtin_amdgcn_s_barrier();
        if (it < 14) STAGE((it + 2) % 3, (it + 2) * 32);
        const __bf16* Al = &As[it % 3][0];
        const __bf16* Bl = &Bs[it % 3][0];
        bf16x8 af[4], bfv[4];
#pragma unroll
        for (int mt = 0; mt < 4; mt++)
            af[mt] = *(const bf16x8*)&Al[((wr >> 4) + mt) * 512 + lane * 8];
#pragma unroll
        for (int nt = 0; nt < 4; nt++)
            bfv[nt] = *(const bf16x8*)&Bl[((wc >> 4) + nt) * 512 + lane * 8];
        __builtin_amdgcn_s_setprio(1);
#pragma unroll
        for (int mt = 0; mt < 4; mt++)
#pragma unroll
            for (int nt = 0; nt < 4; nt++)
                acc[mt][nt] = __builtin_amdgcn_mfma_f32_16x16x32_bf16(
                    af[mt], bfv[nt], acc[mt][nt], 0, 0, 0);
        __builtin_amdgcn_s_setprio(0);
    }
#undef STAGE

    __syncthreads();
    if (tid < 256) zred[tid] = 0.f;
    __syncthreads();

#pragma unroll
    for (int mt = 0; mt < 4; mt++) {
        float esum[4] = {0.f, 0.f, 0.f, 0.f};
#pragma unroll
        for (int nt = 0; nt < 4; nt++) {
            int c = col0 + wc + nt * 16 + l15;
            if (c < VV) {
                float bv = bias[c];
#pragma unroll
                for (int i = 0; i < 4; i++) {
                    int r = row0 + wr + mt * 16 + quad * 4 + i;
                    float l = acc[mt][nt][i] + bv;
                    if (BF16OUT) Cb[(size_t)r * VP + c] = f2b(l);
                    else         Cf[(size_t)r * VV + c] = l;
                    esum[i] += __expf(l);
                }
            }
        }
#pragma unroll
        for (int i = 0; i < 4; i++) {
            float e = esum[i];
            e += __shfl_xor(e, 1);
            e += __shfl_xor(e, 2);
            e += __shfl_xor(e, 4);
            e += __shfl_xor(e, 8);
            if (l15 == 0)
                atomicAdd(&zred[wr + mt * 16 + quad * 4 + i], e);
        }
    }
    __syncthreads();
    if (tid < 256) atomicAdd(&Zrow[row0 + tid], zred[tid]);
}

// ---------------------------------------------------------------------------
// K4 shared preamble (256-thread version, used by fallback k_final_s)
// ---------------------------------------------------------------------------
#define HT 1024
#define NBW 1572   // ceil(VV/32)

__device__ __forceinline__ void build_hash(const int* __restrict__ src,
                                           const float* __restrict__ ap,
                                           int b, int tid,
                                           int* keys, float* vals, unsigned* bmap,
                                           float* red, int* s_D, float* s_Zc) {
    for (int i = tid; i < HT; i += 256) { keys[i] = -1; vals[i] = 0.f; }
    for (int i = tid; i < NBW; i += 256) bmap[i] = 0u;
    if (tid == 0) *s_D = 0;
    __syncthreads();

    for (int s = tid; s < SS; s += 256) {
        int idx = src[s * BB + b];
        float v = ap[s];
        unsigned h = ((unsigned)idx * 2654435761u) >> 22;
        while (true) {
            int old = atomicCAS(&keys[h], -1, idx);
            if (old == -1 || old == idx) { atomicAdd(&vals[h], v); break; }
            h = (h + 1) & (HT - 1);
        }
    }
    __syncthreads();

    float lsum = 0.f; int dloc = 0;
    for (int i = tid; i < HT; i += 256) {
        int k = keys[i];
        if (k != -1) {
            lsum += __expf(vals[i]); dloc++;
            atomicOr(&bmap[(unsigned)k >> 5], 1u << (k & 31));
        }
    }
    atomicAdd(s_D, dloc);
    red[tid] = lsum; __syncthreads();
    for (int st = 128; st > 0; st >>= 1) {
        if (tid < st) red[tid] += red[tid + st];
        __syncthreads();
    }
    if (tid == 0) *s_Zc = (float)(VV - *s_D) + red[0];
    __syncthreads();
}

// ---------------------------------------------------------------------------
// K4a: finalize from bf16 padded logits. Grid (2, MM), 1024 threads. Each
// block also computes its own prob (512-FMA reduce on the attn row it already
// reads) — the separate prob kernel is gone. Clean 8-packs (bitmap byte==0,
// ~92%) take a guard-free path.
// ---------------------------------------------------------------------------
#define HV (VP / 2)   // 25152, multiple of 8
__global__ __launch_bounds__(1024) void k_final2(const int* __restrict__ src,
                                                 const float* __restrict__ attn,
                                                 const float* __restrict__ mw,
                                                 const float* __restrict__ bp,
                                                 const float* __restrict__ Zrow,
                                                 const __bf16* __restrict__ LG,
                                                 float* __restrict__ out) {
    __shared__ int      keys[HT];
    __shared__ float    vals[HT];
    __shared__ unsigned bmap[NBW];
    __shared__ float    red[1024];
    __shared__ float    red2[1024];
    __shared__ int      s_D;
    __shared__ float    s_Zc;
    __shared__ float    s_p;

    int r = blockIdx.y;
    int half = blockIdx.x;
    int t = r / BB, b = r % BB;
    int tid = threadIdx.x;
    const float* ap = attn + ((size_t)b * TT + t) * SS;

    // ---- build hash (1024 threads; HT == 1024) + prob partial ----
    { keys[tid] = -1; vals[tid] = 0.f; }
    for (int i = tid; i < NBW; i += 1024) bmap[i] = 0u;
    if (tid == 0) s_D = 0;
    __syncthreads();

    float pv = 0.f;
    if (tid < SS) {
        int idx = src[tid * BB + b];
        float av = ap[tid];
        pv = av * mw[tid * BB + b];
        unsigned h = ((unsigned)idx * 2654435761u) >> 22;
        while (true) {
            int old = atomicCAS(&keys[h], -1, idx);
            if (old == -1 || old == idx) { atomicAdd(&vals[h], av); break; }
            h = (h + 1) & (HT - 1);
        }
    }
    __syncthreads();

    float lsum = 0.f;
    {
        int k = keys[tid];
        bool occ = (k != -1);
        if (occ) {
            lsum = __expf(vals[tid]);
            atomicOr(&bmap[(unsigned)k >> 5], 1u << (k & 31));
        }
        unsigned long long m = __ballot(occ);
        if ((tid & 63) == 0) atomicAdd(&s_D, __popcll(m));
    }
    red[tid] = lsum; red2[tid] = pv; __syncthreads();
    for (int st = 512; st > 0; st >>= 1) {
        if (tid < st) { red[tid] += red[tid + st]; red2[tid] += red2[tid + st]; }
        __syncthreads();
    }
    if (tid == 0) {
        s_Zc = (float)(VV - s_D) + red[0];
        s_p  = 1.f / (1.f + expf(-(red2[0] + bp[0])));
    }
    __syncthreads();

    float p = s_p;
    float pinvZ = p / Zrow[r];
    float qinvZc = (1.f - p) / s_Zc;

    const __bf16* lrow = LG + (size_t)r * VP;
    float* orow = out + (size_t)r * VV;

    int base = half * HV;
    for (int v0 = base + tid * 8; v0 < base + HV; v0 += 8192) {
        bf16x8 l8 = *(const bf16x8*)&lrow[v0];
        unsigned bits = (bmap[v0 >> 5] >> (v0 & 31)) & 0xFFu;  // v0%8==0
        if (bits == 0u && v0 + 8 <= VV) {
#pragma unroll
            for (int e = 0; e < 8; e++)
                orow[v0 + e] = __logf(pinvZ * __expf((float)l8[e]) + qinvZc);
        } else {
#pragma unroll
            for (int e = 0; e < 8; e++) {
                int v = v0 + e;
                if (v < VV) {
                    float l = (float)l8[e];
                    float c = 1.f;
                    if ((bits >> e) & 1u) {
                        unsigned h = ((unsigned)v * 2654435761u) >> 22;
                        while (true) {
                            int k = keys[h];
                            if (k == v) { c = __expf(vals[h]); break; }
                            if (k == -1) break;
                            h = (h + 1) & (HT - 1);
                        }
                    }
                    orow[v] = __logf(pinvZ * __expf(l) + qinvZc * c);
                }
            }
        }
    }
}

// ---------------------------------------------------------------------------
// K4b: fallback — finalize fp32 logits in-place in d_out (computes own prob)
// ---------------------------------------------------------------------------
#define CHUNKS 6283
__global__ __launch_bounds__(256) void k_final_s(const int* __restrict__ src,
                                                 const float* __restrict__ attn,
                                                 const float* __restrict__ mw,
                                                 const float* __restrict__ bp,
                                                 const float* __restrict__ Zrow,
                                                 float* __restrict__ out) {
    __shared__ int      keys[HT];
    __shared__ float    vals[HT];
    __shared__ unsigned bmap[NBW];
    __shared__ float    red[256];
    __shared__ int      s_D;
    __shared__ float    s_Zc;
    __shared__ float    s_p;

    int r = blockIdx.y;
    int t = r / BB, b = r % BB;
    int tid = threadIdx.x;
    const float* ap = attn + ((size_t)b * TT + t) * SS;

    // prob reduction first (red reused by build_hash afterwards)
    float pacc = ap[tid] * mw[tid * BB + b] +
                 ap[tid + 256] * mw[(tid + 256) * BB + b];
    red[tid] = pacc; __syncthreads();
    for (int st = 128; st > 0; st >>= 1) {
        if (tid < st) red[tid] += red[tid + st];
        __syncthreads();
    }
    if (tid == 0) s_p = 1.f / (1.f + expf(-(red[0] + bp[0])));
    __syncthreads();

    build_hash(src, ap, b, tid, keys, vals, bmap, red, &s_D, &s_Zc);

    float p = s_p;
    float pinvZ = p / Zrow[r];
    float qinvZc = (1.f - p) / s_Zc;

    int c0 = blockIdx.x * CHUNKS;
    int c1 = c0 + CHUNKS; if (c1 > VV) c1 = VV;
    float* rowp = out + (size_t)r * VV;

    for (int v = c0 + tid; v < c1; v += 256) {
        float l = rowp[v];
        float c = 1.f;
        if ((bmap[v >> 5] >> (v & 31)) & 1u) {
            unsigned h = ((unsigned)v * 2654435761u) >> 22;
            while (true) {
                int k = keys[h];
                if (k == v) { c = __expf(vals[h]); break; }
                if (k == -1) break;
                h = (h + 1) & (HT - 1);
            }
        }
        rowp[v] = __logf(pinvZ * __expf(l) + qinvZc * c);
    }
}

// ---------------------------------------------------------------------------
extern "C" void kernel_launch(void* const* d_in, const int* in_sizes, int n_in,
                              void* d_out, int out_size, void* d_ws, size_t ws_size,
                              hipStream_t stream) {
    const int*   src_full      = (const int*)d_in[0];   // [S,B]
    const float* decode_output = (const float*)d_in[1]; // [T,B,H]
    const float* decode_attn   = (const float*)d_in[2]; // [B,T,S]
    const float* memory        = (const float*)d_in[3]; // [S,B,H]
    const float* W_gen         = (const float*)d_in[4]; // [H,V]
    const float* b_gen         = (const float*)d_in[5]; // [V]
    const float* W_prob        = (const float*)d_in[6]; // [H]
    const float* b_prob        = (const float*)d_in[7]; // [1]
    float* out = (float*)d_out;                         // [T,B,V]

    float* ws   = (float*)d_ws;
    float* mw   = ws;                        // 4096 floats
    float* Z    = ws + 4608;                 // 512
    __bf16* Ab  = (__bf16*)(ws + 5120);      // 512*512 bf16
    __bf16* Wt8 = (__bf16*)(ws + 5120 + 131072);   // 64*VP*8 bf16 (51.5 MB)
    __bf16* LG  = Wt8 + (size_t)VP * HH;           // MM*VP bf16 (51.5 MB)

    size_t base_b = (size_t)(5120 + 131072) * sizeof(float);
    size_t wt_b   = (size_t)VP * HH * 2;
    size_t lg_b   = (size_t)MM * VP * 2;
    bool full = ws_size >= base_b + wt_b + lg_b;

    // L1: Wt8 k8-panels (3200) + castA (256) + mw (1024)
    k_pre<<<NW8 + 256 + 1024, 256, 0, stream>>>(
        W_gen, Wt8, decode_output, Ab, memory, W_prob, mw);
    hipMemsetAsync(Z, 0, MM * sizeof(float), stream);

    dim3 ggrid(MM / 256, VP / 128);          // (2, 393)
    if (full) {
        k_gemm7<true><<<ggrid, 512, 0, stream>>>(Ab, Wt8, b_gen, nullptr, LG, Z);
        dim3 fgrid(2, MM);                   // (2, 512)
        k_final2<<<fgrid, 1024, 0, stream>>>(src_full, decode_attn, mw, b_prob,
                                             Z, LG, out);
    } else {
        k_gemm7<false><<<ggrid, 512, 0, stream>>>(Ab, Wt8, b_gen, out, nullptr, Z);
        dim3 fgrid((VV + CHUNKS - 1) / CHUNKS, MM);  // (8, 512)
        k_final_s<<<fgrid, 256, 0, stream>>>(src_full, decode_attn, mw, b_prob,
                                             Z, out);
    }
}